// Round 3
// baseline (133.124 us; speedup 1.0000x reference)
//
#include <hip/hip_runtime.h>

#define Hc     512
#define Wc     512
#define OH     506
#define OW     506
#define NPIX   (Hc * Wc)
#define BATCH  64
#define CHUNKS 16

#define T_OW   64
#define T_OH   16
#define IN_H   (T_OH + 6)          // 22
#define HS_W   65                  // padded row stride in float4 units
#define GX     8                   // ceil(506/64)
#define GY     32                  // ceil(506/16)
#define NPART  (BATCH * GX * GY)   // 16384
#define NRUNS  (IN_H * 16)         // 352 column-runs of 4 per tile

// ---------------- Kernel 1: per-(sample,chunk) min/max partials -------------
__global__ __launch_bounds__(256) void mm_part_kernel(
    const float* __restrict__ X, const float* __restrict__ Y,
    float* __restrict__ part)
{
    int blk = blockIdx.x;            // 0 .. BATCH*CHUNKS-1
    int b   = blk >> 4;
    int ch  = blk & 15;
    size_t base = (size_t)b * NPIX + (size_t)ch * (NPIX / CHUNKS);
    const float4* x4 = (const float4*)(X + base);
    const float4* y4 = (const float4*)(Y + base);
    const int n4 = (NPIX / CHUNKS) / 4;   // 4096

    float mn = 1e38f, mx = -1e38f;
    for (int i = threadIdx.x; i < n4; i += 256) {
        float4 a = x4[i];
        float4 c = y4[i];
        mn = fminf(mn, fminf(fminf(a.x, a.y), fminf(a.z, a.w)));
        mx = fmaxf(mx, fmaxf(fmaxf(a.x, a.y), fmaxf(a.z, a.w)));
        mn = fminf(mn, fminf(fminf(c.x, c.y), fminf(c.z, c.w)));
        mx = fmaxf(mx, fmaxf(fmaxf(c.x, c.y), fmaxf(c.z, c.w)));
    }
    #pragma unroll
    for (int off = 1; off < 64; off <<= 1) {
        mn = fminf(mn, __shfl_xor(mn, off, 64));
        mx = fmaxf(mx, __shfl_xor(mx, off, 64));
    }
    __shared__ float smn[4], smx[4];
    int lane = threadIdx.x & 63, wid = threadIdx.x >> 6;
    if (lane == 0) { smn[wid] = mn; smx[wid] = mx; }
    __syncthreads();
    if (threadIdx.x == 0) {
        mn = fminf(fminf(smn[0], smn[1]), fminf(smn[2], smn[3]));
        mx = fmaxf(fmaxf(smx[0], smx[1]), fmaxf(smx[2], smx[3]));
        part[2 * blk]     = mn;
        part[2 * blk + 1] = mx;
    }
}

// ---------------- Kernel 2: fold chunk partials -> C1, C2 per sample --------
__global__ void mm_final_kernel(const float* __restrict__ part,
                                float* __restrict__ c12)
{
    int b = threadIdx.x;
    if (b < BATCH) {
        float mn = 1e38f, mx = -1e38f;
        #pragma unroll
        for (int ch = 0; ch < CHUNKS; ++ch) {
            mn = fminf(mn, part[2 * (b * CHUNKS + ch)]);
            mx = fmaxf(mx, part[2 * (b * CHUNKS + ch) + 1]);
        }
        float dr = mx - mn;
        float c1 = 0.01f * dr;
        float c2 = 0.03f * dr;
        c12[2 * b]     = c1 * c1;
        c12[2 * b + 1] = c2 * c2;
    }
}

// ---------------- Kernel 3: load-fused horizontal + sliding vertical SSIM ---
__global__ __launch_bounds__(256) void ssim_kernel(
    const float* __restrict__ X, const float* __restrict__ Y,
    const float* __restrict__ c12, float* __restrict__ part)
{
    __shared__ float4 hs[IN_H][HS_W];     // 22*65*16 = 22880 B

    const int b   = blockIdx.z;
    const int oy0 = blockIdx.y * T_OH;
    const int ox0 = blockIdx.x * T_OW;
    const float* xb = X + (size_t)b * NPIX;
    const float* yb = Y + (size_t)b * NPIX;
    const int tid = threadIdx.x;

    const float C1 = c12[2 * b];
    const float C2 = c12[2 * b + 1];

    const bool edge = (ox0 + T_OW + 6 > Wc);   // only last column-tile

    // ---- phase 1: global -> registers -> horizontal 7-sums (sliding) ------
    for (int q = tid; q < NRUNS; q += 256) {
        int r  = q >> 4;
        int c0 = (q & 15) * 4;
        int iy = oy0 + r; if (iy > Hc - 1) iy = Hc - 1;
        const float* xr = xb + (size_t)iy * Wc;
        const float* yr = yb + (size_t)iy * Wc;
        float xv[10], yv[10];
        if (!edge) {
            float4 a0 = *(const float4*)(xr + ox0 + c0);
            float4 a1 = *(const float4*)(xr + ox0 + c0 + 4);
            float2 a2 = *(const float2*)(xr + ox0 + c0 + 8);
            xv[0]=a0.x; xv[1]=a0.y; xv[2]=a0.z; xv[3]=a0.w;
            xv[4]=a1.x; xv[5]=a1.y; xv[6]=a1.z; xv[7]=a1.w;
            xv[8]=a2.x; xv[9]=a2.y;
            float4 b0 = *(const float4*)(yr + ox0 + c0);
            float4 b1 = *(const float4*)(yr + ox0 + c0 + 4);
            float2 b2 = *(const float2*)(yr + ox0 + c0 + 8);
            yv[0]=b0.x; yv[1]=b0.y; yv[2]=b0.z; yv[3]=b0.w;
            yv[4]=b1.x; yv[5]=b1.y; yv[6]=b1.z; yv[7]=b1.w;
            yv[8]=b2.x; yv[9]=b2.y;
        } else {
            #pragma unroll
            for (int j = 0; j < 10; ++j) {
                int ix = ox0 + c0 + j; if (ix > Wc - 1) ix = Wc - 1;
                xv[j] = xr[ix]; yv[j] = yr[ix];
            }
        }
        float pxy[10], pss[10];
        #pragma unroll
        for (int j = 0; j < 10; ++j) {
            pxy[j] = xv[j] * yv[j];
            pss[j] = xv[j] * xv[j] + yv[j] * yv[j];
        }
        float Sx = 0.f, Sy = 0.f, Sxy = 0.f, Sss = 0.f;
        #pragma unroll
        for (int j = 0; j < 7; ++j) {
            Sx += xv[j]; Sy += yv[j]; Sxy += pxy[j]; Sss += pss[j];
        }
        hs[r][c0] = make_float4(Sx, Sy, Sxy, Sss);
        #pragma unroll
        for (int s = 0; s < 3; ++s) {
            Sx  += xv[7 + s]  - xv[s];
            Sy  += yv[7 + s]  - yv[s];
            Sxy += pxy[7 + s] - pxy[s];
            Sss += pss[7 + s] - pss[s];
            hs[r][c0 + 1 + s] = make_float4(Sx, Sy, Sxy, Sss);
        }
    }
    __syncthreads();

    // ---- phase 2: vertical sliding 7-sums + SSIM ---------------------------
    const int c  = tid & 63;
    const int r0 = (tid >> 6) * 4;      // 4 output rows per thread
    float4 h[7];
    #pragma unroll
    for (int k = 0; k < 7; ++k) h[k] = hs[r0 + k][c];
    float Sx = 0.f, Sy = 0.f, Sxy = 0.f, Sss = 0.f;
    #pragma unroll
    for (int k = 0; k < 7; ++k) {
        Sx += h[k].x; Sy += h[k].y; Sxy += h[k].z; Sss += h[k].w;
    }

    const float inv  = 1.0f / 49.0f;
    const float covn = 49.0f / 48.0f;
    const int ox = ox0 + c;
    float acc = 0.f;
    #pragma unroll
    for (int j = 0; j < 4; ++j) {
        int oy = oy0 + r0 + j;
        float ux   = Sx * inv, uy = Sy * inv;
        float uxuy = ux * uy;
        float u2   = ux * ux + uy * uy;
        float vxy  = covn * (Sxy * inv - uxuy);
        float vsum = covn * (Sss * inv - u2);
        float A1v  = 2.f * uxuy + C1;
        float A2v  = 2.f * vxy + C2;
        float B1v  = u2 + C1;
        float B2v  = vsum + C2;
        float sv   = (A1v * A2v) * __builtin_amdgcn_rcpf(B1v * B2v);
        acc += (oy < OH && ox < OW) ? sv : 0.f;
        if (j < 3) {
            float4 nh = hs[r0 + j + 7][c];
            Sx  += nh.x - h[j].x;
            Sy  += nh.y - h[j].y;
            Sxy += nh.z - h[j].z;
            Sss += nh.w - h[j].w;
        }
    }

    // ---- deterministic block reduce ---------------------------------------
    #pragma unroll
    for (int off = 1; off < 64; off <<= 1)
        acc += __shfl_xor(acc, off, 64);
    __shared__ float sacc[4];
    int lane = tid & 63, wid = tid >> 6;
    if (lane == 0) sacc[wid] = acc;
    __syncthreads();
    if (tid == 0) {
        float s = sacc[0] + sacc[1] + sacc[2] + sacc[3];
        part[((size_t)b * GY + blockIdx.y) * GX + blockIdx.x] = s;
    }
}

// ---------------- Kernel 4: final deterministic f64 reduction ---------------
__global__ __launch_bounds__(1024) void final_reduce_kernel(
    const float* __restrict__ part, float* __restrict__ out)
{
    __shared__ double sd[1024];
    double s = 0.0;
    for (int i = threadIdx.x; i < NPART; i += 1024)
        s += (double)part[i];
    sd[threadIdx.x] = s;
    __syncthreads();
    for (int off = 512; off > 0; off >>= 1) {
        if (threadIdx.x < off) sd[threadIdx.x] += sd[threadIdx.x + off];
        __syncthreads();
    }
    if (threadIdx.x == 0)
        out[0] = (float)(sd[0] / ((double)BATCH * OH * OW));
}

extern "C" void kernel_launch(void* const* d_in, const int* in_sizes, int n_in,
                              void* d_out, int out_size, void* d_ws, size_t ws_size,
                              hipStream_t stream) {
    const float* X = (const float*)d_in[0];
    const float* Y = (const float*)d_in[1];
    float* out = (float*)d_out;
    float* ws  = (float*)d_ws;

    float* mmpart = ws;                 // 2 * BATCH * CHUNKS = 2048 floats
    float* c12    = ws + 2048;          // 2 * BATCH = 128 floats
    float* part   = ws + 2048 + 128;    // NPART = 16384 floats

    mm_part_kernel<<<BATCH * CHUNKS, 256, 0, stream>>>(X, Y, mmpart);
    mm_final_kernel<<<1, 64, 0, stream>>>(mmpart, c12);
    dim3 grid(GX, GY, BATCH);
    ssim_kernel<<<grid, 256, 0, stream>>>(X, Y, c12, part);
    final_reduce_kernel<<<1, 1024, 0, stream>>>(part, out);
}

// Round 4
// 93.519 us; speedup vs baseline: 1.4235x; 1.4235x over previous
//
#include <hip/hip_runtime.h>

#define Hc     512
#define Wc     512
#define OH     506
#define OW     506
#define NPIX   (Hc * Wc)
#define BATCH  64
#define CHUNKS 16

#define CPW    58                          // useful output cols per wave
#define NCHUNK 9                           // 9*58 = 522 >= 506
#define BH     64                          // output rows per band
#define NBAND  8                           // 8*64 = 512 >= 506
#define NPART  (BATCH * NBAND * NCHUNK)    // 4608

// ---------------- Kernel 1: per-(sample,chunk) min/max partials -------------
__global__ __launch_bounds__(256) void mm_part_kernel(
    const float* __restrict__ X, const float* __restrict__ Y,
    float* __restrict__ part)
{
    int blk = blockIdx.x;            // 0 .. BATCH*CHUNKS-1
    int b   = blk >> 4;
    int ch  = blk & 15;
    size_t base = (size_t)b * NPIX + (size_t)ch * (NPIX / CHUNKS);
    const float4* x4 = (const float4*)(X + base);
    const float4* y4 = (const float4*)(Y + base);
    const int n4 = (NPIX / CHUNKS) / 4;   // 4096

    float mn = 1e38f, mx = -1e38f;
    for (int i = threadIdx.x; i < n4; i += 256) {
        float4 a = x4[i];
        float4 c = y4[i];
        mn = fminf(mn, fminf(fminf(a.x, a.y), fminf(a.z, a.w)));
        mx = fmaxf(mx, fmaxf(fmaxf(a.x, a.y), fmaxf(a.z, a.w)));
        mn = fminf(mn, fminf(fminf(c.x, c.y), fminf(c.z, c.w)));
        mx = fmaxf(mx, fmaxf(fmaxf(c.x, c.y), fmaxf(c.z, c.w)));
    }
    #pragma unroll
    for (int off = 1; off < 64; off <<= 1) {
        mn = fminf(mn, __shfl_xor(mn, off, 64));
        mx = fmaxf(mx, __shfl_xor(mx, off, 64));
    }
    __shared__ float smn[4], smx[4];
    int lane = threadIdx.x & 63, wid = threadIdx.x >> 6;
    if (lane == 0) { smn[wid] = mn; smx[wid] = mx; }
    __syncthreads();
    if (threadIdx.x == 0) {
        mn = fminf(fminf(smn[0], smn[1]), fminf(smn[2], smn[3]));
        mx = fmaxf(fmaxf(smx[0], smx[1]), fmaxf(smx[2], smx[3]));
        part[2 * blk]     = mn;
        part[2 * blk + 1] = mx;
    }
}

// ---------------- horizontal 7-window sum across lanes ----------------------
__device__ __forceinline__ float h7(float v) {
    float t1 = v + __shfl_down(v, 1, 64);      // [c, c+1]
    float t2 = t1 + __shfl_down(t1, 2, 64);    // [c .. c+3]
    return t2 + __shfl_down(t1, 4, 64)         // [c+4, c+5]
              + __shfl_down(v, 6, 64);         // [c+6]
}

// ---------------- Kernel 2: barrier-free streaming SSIM ---------------------
// One wave per (img, band, col-chunk). Vertical 7-window via register ring,
// horizontal 7-window via cross-lane shuffles. No LDS, no __syncthreads.
__global__ __launch_bounds__(64) void ssim_stream_kernel(
    const float* __restrict__ X, const float* __restrict__ Y,
    const float* __restrict__ mmpart, float* __restrict__ part)
{
    const int lane  = threadIdx.x;
    const int chunk = blockIdx.x;       // 0..8
    const int band  = blockIdx.y;       // 0..7
    const int img   = blockIdx.z;       // 0..63

    // fold chunk min/max -> C1, C2 (uniform; hidden under prologue loads)
    float mn = 1e38f, mx = -1e38f;
    #pragma unroll
    for (int ch = 0; ch < CHUNKS; ++ch) {
        mn = fminf(mn, mmpart[2 * (img * CHUNKS + ch)]);
        mx = fmaxf(mx, mmpart[2 * (img * CHUNKS + ch) + 1]);
    }
    const float dr = mx - mn;
    const float C1 = (0.01f * dr) * (0.01f * dr);
    const float C2 = (0.03f * dr) * (0.03f * dr);

    const int col = chunk * CPW + lane;
    const int lc  = col < (Wc - 1) ? col : (Wc - 1);   // clamped load col
    const int oy0 = band * BH;
    const int nvalid  = (OH - oy0) < BH ? (OH - oy0) : BH;   // 64 or 58
    const int ngroups = (nvalid + 6) / 7;                    // 10 or 9
    const float vmask = (lane < CPW && col < OW) ? 1.0f : 0.0f;

    const float* px = X + (size_t)img * NPIX + lc;
    const float* py = Y + (size_t)img * NPIX + lc;

    // vertical ring (raw values) + running vertical sums
    float rx[7], ry[7];
    float Vx = 0.f, Vy = 0.f, Vxy = 0.f, Vss = 0.f;
    #pragma unroll
    for (int k = 0; k < 6; ++k) {
        float xv = px[(size_t)(oy0 + k) * Wc];
        float yv = py[(size_t)(oy0 + k) * Wc];
        rx[k] = xv; ry[k] = yv;
        Vx += xv; Vy += yv; Vxy += xv * yv; Vss += xv * xv + yv * yv;
    }
    rx[6] = 0.f; ry[6] = 0.f;

    const float inv  = 1.0f / 49.0f;
    const float covn = 49.0f / 48.0f;
    float acc = 0.f;

    for (int g = 0; g < ngroups; ++g) {
        #pragma unroll
        for (int k = 0; k < 7; ++k) {
            const int tt = g * 7 + k;           // output-row index in band
            int ly = oy0 + tt + 6;
            if (ly > Hc - 1) ly = Hc - 1;
            float xv = px[(size_t)ly * Wc];
            float yv = py[(size_t)ly * Wc];
            // window rows [tt, tt+6] complete:
            Vx += xv; Vy += yv; Vxy += xv * yv; Vss += xv * xv + yv * yv;
            if (tt < nvalid) {                  // wave-uniform guard
                float Wx = h7(Vx), Wy = h7(Vy);
                float Wxy = h7(Vxy), Wss = h7(Vss);
                float ux   = Wx * inv, uy = Wy * inv;
                float uxuy = ux * uy;
                float u2   = ux * ux + uy * uy;
                float vxy  = covn * (Wxy * inv - uxuy);
                float vss  = covn * (Wss * inv - u2);
                float A1   = 2.f * uxuy + C1;
                float A2   = 2.f * vxy + C2;
                float B1   = u2 + C1;
                float B2   = vss + C2;
                float s    = (A1 * A2) * __builtin_amdgcn_rcpf(B1 * B2);
                acc = fmaf(s, vmask, acc);
            }
            // slide: drop row tt (slot k), insert row tt+6 (slot (k+6)%7)
            float ox = rx[k], oyv = ry[k];
            Vx -= ox; Vy -= oyv; Vxy -= ox * oyv; Vss -= ox * ox + oyv * oyv;
            rx[(k + 6) % 7] = xv; ry[(k + 6) % 7] = yv;
        }
    }

    // deterministic wave reduce
    #pragma unroll
    for (int off = 1; off < 64; off <<= 1)
        acc += __shfl_xor(acc, off, 64);
    if (lane == 0)
        part[((size_t)img * NBAND + band) * NCHUNK + chunk] = acc;
}

// ---------------- Kernel 3: final deterministic f64 reduction ---------------
__global__ __launch_bounds__(1024) void final_reduce_kernel(
    const float* __restrict__ part, float* __restrict__ out)
{
    __shared__ double sd[1024];
    double s = 0.0;
    for (int i = threadIdx.x; i < NPART; i += 1024)
        s += (double)part[i];
    sd[threadIdx.x] = s;
    __syncthreads();
    for (int off = 512; off > 0; off >>= 1) {
        if (threadIdx.x < off) sd[threadIdx.x] += sd[threadIdx.x + off];
        __syncthreads();
    }
    if (threadIdx.x == 0)
        out[0] = (float)(sd[0] / ((double)BATCH * OH * OW));
}

extern "C" void kernel_launch(void* const* d_in, const int* in_sizes, int n_in,
                              void* d_out, int out_size, void* d_ws, size_t ws_size,
                              hipStream_t stream) {
    const float* X = (const float*)d_in[0];
    const float* Y = (const float*)d_in[1];
    float* out = (float*)d_out;
    float* ws  = (float*)d_ws;

    float* mmpart = ws;                 // 2 * BATCH * CHUNKS = 2048 floats
    float* part   = ws + 2048;          // NPART = 4608 floats

    mm_part_kernel<<<BATCH * CHUNKS, 256, 0, stream>>>(X, Y, mmpart);
    dim3 grid(NCHUNK, NBAND, BATCH);
    ssim_stream_kernel<<<grid, 64, 0, stream>>>(X, Y, mmpart, part);
    final_reduce_kernel<<<1, 1024, 0, stream>>>(part, out);
}

// Round 5
// 91.184 us; speedup vs baseline: 1.4600x; 1.0256x over previous
//
#include <hip/hip_runtime.h>

#define Hc     512
#define Wc     512
#define OH     506
#define OW     506
#define NPIX   (Hc * Wc)
#define BATCH  64
#define CHUNKS 16

#define CPW    58                          // useful output cols per wave
#define NCHUNK 9                           // 9*58 = 522 >= 506
#define BH     32                          // output rows per band
#define NBAND  16                          // 16*32 = 512 >= 506
#define WPB    4                           // waves per block
#define NPART  (BATCH * NBAND * NCHUNK)    // 9216

// ---------------- Kernel 1: per-(sample,chunk) min/max partials -------------
__global__ __launch_bounds__(256) void mm_part_kernel(
    const float* __restrict__ X, const float* __restrict__ Y,
    float* __restrict__ part)
{
    int blk = blockIdx.x;            // 0 .. BATCH*CHUNKS-1
    int b   = blk >> 4;
    int ch  = blk & 15;
    size_t base = (size_t)b * NPIX + (size_t)ch * (NPIX / CHUNKS);
    const float4* x4 = (const float4*)(X + base);
    const float4* y4 = (const float4*)(Y + base);
    const int n4 = (NPIX / CHUNKS) / 4;   // 4096

    float mn = 1e38f, mx = -1e38f;
    for (int i = threadIdx.x; i < n4; i += 256) {
        float4 a = x4[i];
        float4 c = y4[i];
        mn = fminf(mn, fminf(fminf(a.x, a.y), fminf(a.z, a.w)));
        mx = fmaxf(mx, fmaxf(fmaxf(a.x, a.y), fmaxf(a.z, a.w)));
        mn = fminf(mn, fminf(fminf(c.x, c.y), fminf(c.z, c.w)));
        mx = fmaxf(mx, fmaxf(fmaxf(c.x, c.y), fmaxf(c.z, c.w)));
    }
    #pragma unroll
    for (int off = 1; off < 64; off <<= 1) {
        mn = fminf(mn, __shfl_xor(mn, off, 64));
        mx = fmaxf(mx, __shfl_xor(mx, off, 64));
    }
    __shared__ float smn[4], smx[4];
    int lane = threadIdx.x & 63, wid = threadIdx.x >> 6;
    if (lane == 0) { smn[wid] = mn; smx[wid] = mx; }
    __syncthreads();
    if (threadIdx.x == 0) {
        mn = fminf(fminf(smn[0], smn[1]), fminf(smn[2], smn[3]));
        mx = fmaxf(fmaxf(smx[0], smx[1]), fmaxf(smx[2], smx[3]));
        part[2 * blk]     = mn;
        part[2 * blk + 1] = mx;
    }
}

// ---------------- horizontal 7-window sum across lanes ----------------------
__device__ __forceinline__ float h7(float v) {
    float t1 = v + __shfl_down(v, 1, 64);      // [c, c+1]
    float t2 = t1 + __shfl_down(t1, 2, 64);    // [c .. c+3]
    return t2 + __shfl_down(t1, 4, 64)         // [c+4, c+5]
              + __shfl_down(v, 6, 64);         // [c+6]
}

// ---------------- Kernel 2: barrier-free streaming SSIM ---------------------
// One wave per (img, band, col-chunk); 4 bands per 256-thread block.
// Vertical 7-window via register ring, horizontal via cross-lane shuffles.
// No LDS, no __syncthreads.
__global__ __launch_bounds__(256) void ssim_stream_kernel(
    const float* __restrict__ X, const float* __restrict__ Y,
    const float* __restrict__ mmpart, float* __restrict__ part)
{
    const int lane  = threadIdx.x & 63;
    const int wid   = threadIdx.x >> 6;
    const int chunk = blockIdx.x;               // 0..8
    const int band  = blockIdx.y * WPB + wid;   // 0..15
    const int img   = blockIdx.z;               // 0..63

    // fold chunk min/max -> C1, C2 (uniform; hidden under prologue loads)
    float mn = 1e38f, mx = -1e38f;
    #pragma unroll
    for (int ch = 0; ch < CHUNKS; ++ch) {
        mn = fminf(mn, mmpart[2 * (img * CHUNKS + ch)]);
        mx = fmaxf(mx, mmpart[2 * (img * CHUNKS + ch) + 1]);
    }
    const float dr = mx - mn;
    const float C1 = (0.01f * dr) * (0.01f * dr);
    const float C2 = (0.03f * dr) * (0.03f * dr);

    const int col = chunk * CPW + lane;
    const int lc  = col < (Wc - 1) ? col : (Wc - 1);   // clamped load col
    const int oy0 = band * BH;
    const int nvalid  = (OH - oy0) < BH ? (OH - oy0) : BH;   // 32 or 26
    const int ngroups = (nvalid + 6) / 7;                    // 5 or 4
    const float vmask = (lane < CPW && col < OW) ? 1.0f : 0.0f;

    const float* px = X + (size_t)img * NPIX + lc;
    const float* py = Y + (size_t)img * NPIX + lc;

    // vertical ring (raw values) + running vertical sums
    float rx[7], ry[7];
    float Vx = 0.f, Vy = 0.f, Vxy = 0.f, Vss = 0.f;
    #pragma unroll
    for (int k = 0; k < 6; ++k) {
        float xv = px[(size_t)(oy0 + k) * Wc];
        float yv = py[(size_t)(oy0 + k) * Wc];
        rx[k] = xv; ry[k] = yv;
        Vx += xv; Vy += yv; Vxy += xv * yv; Vss += xv * xv + yv * yv;
    }
    rx[6] = 0.f; ry[6] = 0.f;

    const float inv  = 1.0f / 49.0f;
    const float covn = 49.0f / 48.0f;
    float acc = 0.f;

    for (int g = 0; g < ngroups; ++g) {
        #pragma unroll
        for (int k = 0; k < 7; ++k) {
            const int tt = g * 7 + k;           // output-row index in band
            int ly = oy0 + tt + 6;
            if (ly > Hc - 1) ly = Hc - 1;
            float xv = px[(size_t)ly * Wc];
            float yv = py[(size_t)ly * Wc];
            // window rows [tt, tt+6] complete:
            Vx += xv; Vy += yv; Vxy += xv * yv; Vss += xv * xv + yv * yv;
            if (tt < nvalid) {                  // wave-uniform guard
                float Wx = h7(Vx), Wy = h7(Vy);
                float Wxy = h7(Vxy), Wss = h7(Vss);
                float ux   = Wx * inv, uy = Wy * inv;
                float uxuy = ux * uy;
                float u2   = ux * ux + uy * uy;
                float vxy  = covn * (Wxy * inv - uxuy);
                float vss  = covn * (Wss * inv - u2);
                float A1   = 2.f * uxuy + C1;
                float A2   = 2.f * vxy + C2;
                float B1   = u2 + C1;
                float B2   = vss + C2;
                float s    = (A1 * A2) * __builtin_amdgcn_rcpf(B1 * B2);
                acc = fmaf(s, vmask, acc);
            }
            // slide: drop row tt (slot k), insert row tt+6 (slot (k+6)%7)
            float ox = rx[k], oyv = ry[k];
            Vx -= ox; Vy -= oyv; Vxy -= ox * oyv; Vss -= ox * ox + oyv * oyv;
            rx[(k + 6) % 7] = xv; ry[(k + 6) % 7] = yv;
        }
    }

    // deterministic wave reduce
    #pragma unroll
    for (int off = 1; off < 64; off <<= 1)
        acc += __shfl_xor(acc, off, 64);
    if (lane == 0)
        part[((size_t)img * NBAND + band) * NCHUNK + chunk] = acc;
}

// ---------------- Kernel 3: final deterministic f64 reduction ---------------
__global__ __launch_bounds__(1024) void final_reduce_kernel(
    const float* __restrict__ part, float* __restrict__ out)
{
    __shared__ double sd[1024];
    double s = 0.0;
    for (int i = threadIdx.x; i < NPART; i += 1024)
        s += (double)part[i];
    sd[threadIdx.x] = s;
    __syncthreads();
    for (int off = 512; off > 0; off >>= 1) {
        if (threadIdx.x < off) sd[threadIdx.x] += sd[threadIdx.x + off];
        __syncthreads();
    }
    if (threadIdx.x == 0)
        out[0] = (float)(sd[0] / ((double)BATCH * OH * OW));
}

extern "C" void kernel_launch(void* const* d_in, const int* in_sizes, int n_in,
                              void* d_out, int out_size, void* d_ws, size_t ws_size,
                              hipStream_t stream) {
    const float* X = (const float*)d_in[0];
    const float* Y = (const float*)d_in[1];
    float* out = (float*)d_out;
    float* ws  = (float*)d_ws;

    float* mmpart = ws;                 // 2 * BATCH * CHUNKS = 2048 floats
    float* part   = ws + 2048;          // NPART = 9216 floats

    mm_part_kernel<<<BATCH * CHUNKS, 256, 0, stream>>>(X, Y, mmpart);
    dim3 grid(NCHUNK, NBAND / WPB, BATCH);
    ssim_stream_kernel<<<grid, 64 * WPB, 0, stream>>>(X, Y, mmpart, part);
    final_reduce_kernel<<<1, 1024, 0, stream>>>(part, out);
}

// Round 6
// 84.819 us; speedup vs baseline: 1.5695x; 1.0750x over previous
//
#include <hip/hip_runtime.h>

#define Hc     512
#define Wc     512
#define OH     506
#define OW     506
#define NPIX   (Hc * Wc)
#define BATCH  64
#define CHUNKS 16

#define BH     16                          // output rows per band
#define NBAND  32                          // 32*16 = 512 >= 506
#define NW     3                           // waves per image-row span
#define WPB    4                           // waves per block
#define NPART  (BATCH * NBAND * NW)        // 6144

// ---------------- Kernel 1: per-(sample,chunk) min/max partials -------------
__global__ __launch_bounds__(256) void mm_part_kernel(
    const float* __restrict__ X, const float* __restrict__ Y,
    float* __restrict__ part)
{
    int blk = blockIdx.x;            // 0 .. BATCH*CHUNKS-1
    int b   = blk >> 4;
    int ch  = blk & 15;
    size_t base = (size_t)b * NPIX + (size_t)ch * (NPIX / CHUNKS);
    const float4* x4 = (const float4*)(X + base);
    const float4* y4 = (const float4*)(Y + base);
    const int n4 = (NPIX / CHUNKS) / 4;   // 4096

    float mn = 1e38f, mx = -1e38f;
    for (int i = threadIdx.x; i < n4; i += 256) {
        float4 a = x4[i];
        float4 c = y4[i];
        mn = fminf(mn, fminf(fminf(a.x, a.y), fminf(a.z, a.w)));
        mx = fmaxf(mx, fmaxf(fmaxf(a.x, a.y), fmaxf(a.z, a.w)));
        mn = fminf(mn, fminf(fminf(c.x, c.y), fminf(c.z, c.w)));
        mx = fmaxf(mx, fmaxf(fmaxf(c.x, c.y), fmaxf(c.z, c.w)));
    }
    #pragma unroll
    for (int off = 1; off < 64; off <<= 1) {
        mn = fminf(mn, __shfl_xor(mn, off, 64));
        mx = fmaxf(mx, __shfl_xor(mx, off, 64));
    }
    __shared__ float smn[4], smx[4];
    int lane = threadIdx.x & 63, wid = threadIdx.x >> 6;
    if (lane == 0) { smn[wid] = mn; smx[wid] = mx; }
    __syncthreads();
    if (threadIdx.x == 0) {
        mn = fminf(fminf(smn[0], smn[1]), fminf(smn[2], smn[3]));
        mx = fmaxf(fmaxf(smx[0], smx[1]), fmaxf(smx[2], smx[3]));
        part[2 * blk]     = mn;
        part[2 * blk + 1] = mx;
    }
}

// ---------------- Kernel 2: 4-col/lane streaming SSIM -----------------------
// Each wave: 4 consecutive cols/lane (float4), covers 256 cols; 3 waves span
// a row (bases 0/248/496). Vertical 7-window = running sums + re-load of the
// outgoing row (L1/L2-hot). Horizontal 7-window = 6 independent shuffles/stat
// + in-register sliding. No LDS, no barriers, no ring rotation.
__global__ __launch_bounds__(256, 6) void ssim_stream_kernel(
    const float* __restrict__ X, const float* __restrict__ Y,
    const float* __restrict__ mmpart, float* __restrict__ part)
{
    const int lane  = threadIdx.x & 63;
    const int wid   = threadIdx.x >> 6;
    const int chunk = blockIdx.x;               // 0..2
    const int band  = blockIdx.y * WPB + wid;   // 0..31
    const int img   = blockIdx.z;               // 0..63

    // fold chunk min/max -> C1, C2 (uniform; hidden under prologue loads)
    float mn = 1e38f, mx = -1e38f;
    #pragma unroll
    for (int ch = 0; ch < CHUNKS; ++ch) {
        mn = fminf(mn, mmpart[2 * (img * CHUNKS + ch)]);
        mx = fmaxf(mx, mmpart[2 * (img * CHUNKS + ch) + 1]);
    }
    const float dr = mx - mn;
    const float C1 = (0.01f * dr) * (0.01f * dr);
    const float C2 = (0.03f * dr) * (0.03f * dr);

    // chunk geometry
    const int cbase  = (chunk == 0) ? 0 : (chunk == 1) ? 248 : 496;
    const int out_lo = (chunk == 0) ? 0 : (chunk == 1) ? 250 : 498;
    const int out_hi = (chunk == 0) ? 249 : (chunk == 1) ? 497 : 505;

    const int col0  = cbase + 4 * lane;             // logical first col
    const int col0c = (col0 < 508) ? col0 : 508;    // clamped, 16B aligned
    float vm[4];
    #pragma unroll
    for (int j = 0; j < 4; ++j) {
        int oc = col0 + j;
        vm[j] = (oc >= out_lo && oc <= out_hi) ? 1.0f : 0.0f;
    }

    const int oy0 = band * BH;
    const int nvalid = (OH - oy0) < BH ? (OH - oy0) : BH;   // 16 or 10

    const float* px = X + (size_t)img * NPIX + col0c;
    const float* py = Y + (size_t)img * NPIX + col0c;

    // running vertical sums for own 4 columns
    float Vx[4] = {0,0,0,0}, Vy[4] = {0,0,0,0};
    float Vxy[4] = {0,0,0,0}, Vss[4] = {0,0,0,0};

    #pragma unroll
    for (int k = 0; k < 6; ++k) {
        float4 xa = *(const float4*)(px + (size_t)(oy0 + k) * Wc);
        float4 ya = *(const float4*)(py + (size_t)(oy0 + k) * Wc);
        const float xs[4] = {xa.x, xa.y, xa.z, xa.w};
        const float ys[4] = {ya.x, ya.y, ya.z, ya.w};
        #pragma unroll
        for (int i = 0; i < 4; ++i) {
            Vx[i] += xs[i]; Vy[i] += ys[i];
            Vxy[i] = fmaf(xs[i], ys[i], Vxy[i]);
            Vss[i] += fmaf(xs[i], xs[i], ys[i] * ys[i]);
        }
    }

    const float inv  = 1.0f / 49.0f;
    const float covn = 49.0f / 48.0f;
    float acc = 0.f;

    #pragma unroll 2
    for (int tt = 0; tt < nvalid; ++tt) {
        // add incoming row (oy0+tt+6), max index 511 -> no clamp needed
        float4 xa = *(const float4*)(px + (size_t)(oy0 + tt + 6) * Wc);
        float4 ya = *(const float4*)(py + (size_t)(oy0 + tt + 6) * Wc);
        {
            const float xs[4] = {xa.x, xa.y, xa.z, xa.w};
            const float ys[4] = {ya.x, ya.y, ya.z, ya.w};
            #pragma unroll
            for (int i = 0; i < 4; ++i) {
                Vx[i] += xs[i]; Vy[i] += ys[i];
                Vxy[i] = fmaf(xs[i], ys[i], Vxy[i]);
                Vss[i] += fmaf(xs[i], xs[i], ys[i] * ys[i]);
            }
        }

        // horizontal 7-window: 6 independent shuffles per stat + slide
        #define H7BLOCK(V, S0, S1, S2, S3)                                   \
        {                                                                    \
            float n0 = __shfl_down(V[0], 1, 64);                             \
            float n1 = __shfl_down(V[1], 1, 64);                             \
            float n2 = __shfl_down(V[2], 1, 64);                             \
            float n3 = __shfl_down(V[3], 1, 64);                             \
            float m0 = __shfl_down(V[0], 2, 64);                             \
            float m1 = __shfl_down(V[1], 2, 64);                             \
            S0 = ((V[0] + V[1]) + (V[2] + V[3])) + ((n0 + n1) + n2);         \
            S1 = S0 + n3 - V[0];                                             \
            S2 = S1 + m0 - V[1];                                             \
            S3 = S2 + m1 - V[2];                                             \
        }
        float Wx0, Wx1, Wx2, Wx3;   H7BLOCK(Vx,  Wx0, Wx1, Wx2, Wx3)
        float Wy0, Wy1, Wy2, Wy3;   H7BLOCK(Vy,  Wy0, Wy1, Wy2, Wy3)
        float Wp0, Wp1, Wp2, Wp3;   H7BLOCK(Vxy, Wp0, Wp1, Wp2, Wp3)
        float Ws0, Ws1, Ws2, Ws3;   H7BLOCK(Vss, Ws0, Ws1, Ws2, Ws3)
        #undef H7BLOCK

        #define SSIM1(WxJ, WyJ, WpJ, WsJ, J)                                 \
        {                                                                    \
            float ux   = WxJ * inv, uy = WyJ * inv;                          \
            float uxuy = ux * uy;                                            \
            float u2   = fmaf(ux, ux, uy * uy);                              \
            float vxy  = covn * (WpJ * inv - uxuy);                          \
            float vss  = covn * (WsJ * inv - u2);                            \
            float A1   = fmaf(2.f, uxuy, C1);                                \
            float A2   = fmaf(2.f, vxy, C2);                                 \
            float B1   = u2 + C1;                                            \
            float B2   = vss + C2;                                           \
            float s    = (A1 * A2) * __builtin_amdgcn_rcpf(B1 * B2);         \
            acc = fmaf(s, vm[J], acc);                                       \
        }
        SSIM1(Wx0, Wy0, Wp0, Ws0, 0)
        SSIM1(Wx1, Wy1, Wp1, Ws1, 1)
        SSIM1(Wx2, Wy2, Wp2, Ws2, 2)
        SSIM1(Wx3, Wy3, Wp3, Ws3, 3)
        #undef SSIM1

        // subtract outgoing row (oy0+tt), re-loaded from L1/L2
        float4 xo = *(const float4*)(px + (size_t)(oy0 + tt) * Wc);
        float4 yo = *(const float4*)(py + (size_t)(oy0 + tt) * Wc);
        {
            const float xs[4] = {xo.x, xo.y, xo.z, xo.w};
            const float ys[4] = {yo.x, yo.y, yo.z, yo.w};
            #pragma unroll
            for (int i = 0; i < 4; ++i) {
                Vx[i] -= xs[i]; Vy[i] -= ys[i];
                Vxy[i] = fmaf(-xs[i], ys[i], Vxy[i]);
                Vss[i] -= fmaf(xs[i], xs[i], ys[i] * ys[i]);
            }
        }
    }

    // deterministic wave reduce
    #pragma unroll
    for (int off = 1; off < 64; off <<= 1)
        acc += __shfl_xor(acc, off, 64);
    if (lane == 0)
        part[((size_t)img * NBAND + band) * NW + chunk] = acc;
}

// ---------------- Kernel 3: final deterministic f64 reduction ---------------
__global__ __launch_bounds__(1024) void final_reduce_kernel(
    const float* __restrict__ part, float* __restrict__ out)
{
    __shared__ double sd[1024];
    double s = 0.0;
    for (int i = threadIdx.x; i < NPART; i += 1024)
        s += (double)part[i];
    sd[threadIdx.x] = s;
    __syncthreads();
    for (int off = 512; off > 0; off >>= 1) {
        if (threadIdx.x < off) sd[threadIdx.x] += sd[threadIdx.x + off];
        __syncthreads();
    }
    if (threadIdx.x == 0)
        out[0] = (float)(sd[0] / ((double)BATCH * OH * OW));
}

extern "C" void kernel_launch(void* const* d_in, const int* in_sizes, int n_in,
                              void* d_out, int out_size, void* d_ws, size_t ws_size,
                              hipStream_t stream) {
    const float* X = (const float*)d_in[0];
    const float* Y = (const float*)d_in[1];
    float* out = (float*)d_out;
    float* ws  = (float*)d_ws;

    float* mmpart = ws;                 // 2 * BATCH * CHUNKS = 2048 floats
    float* part   = ws + 2048;          // NPART = 6144 floats

    mm_part_kernel<<<BATCH * CHUNKS, 256, 0, stream>>>(X, Y, mmpart);
    dim3 grid(NW, NBAND / WPB, BATCH);
    ssim_stream_kernel<<<grid, 64 * WPB, 0, stream>>>(X, Y, mmpart, part);
    final_reduce_kernel<<<1, 1024, 0, stream>>>(part, out);
}